// Round 3
// baseline (793.711 us; speedup 1.0000x reference)
//
#include <hip/hip_runtime.h>
#include <math.h>

typedef unsigned int u32;
typedef unsigned short u16;

__device__ inline float bf_lo(u32 v) { return __uint_as_float(v << 16); }
__device__ inline float bf_hi(u32 v) { return __uint_as_float(v & 0xFFFF0000u); }
__device__ inline u16 f2bf(float f) {
    u32 u = __float_as_uint(f);
    return (u16)((u + 0x7FFFu + ((u >> 16) & 1u)) >> 16);
}

// ---------------------------------------------------------------- CSR build
__global__ __launch_bounds__(256) void k_hist(const int* __restrict__ dst,
                                              int* __restrict__ deg, int E) {
    int e = blockIdx.x * 256 + threadIdx.x;
    if (e < E) atomicAdd(&deg[dst[e]], 1);
}

// single block, 1024 threads: rowptr = exclusive_scan(deg)
__global__ __launch_bounds__(1024) void k_scan(const int* __restrict__ deg,
                                               int* __restrict__ rowptr, int n) {
    __shared__ int ws[16];
    const int t = threadIdx.x;
    const int lane = t & 63;
    const int chunk = (n + 1023) >> 10;
    const int lo = t * chunk;
    const int hi = (lo + chunk < n) ? lo + chunk : n;
    int s = 0;
    for (int i = lo; i < hi; ++i) s += deg[i];
    // wave inclusive scan
    int x = s;
#pragma unroll
    for (int o = 1; o < 64; o <<= 1) {
        int y = __shfl_up(x, o, 64);
        if (lane >= o) x += y;
    }
    if (lane == 63) ws[t >> 6] = x;
    __syncthreads();
    if (t < 16) {
        int v = ws[t];
#pragma unroll
        for (int o = 1; o < 16; o <<= 1) {
            int y = __shfl_up(v, o, 64);
            if (lane >= o) v += y;
        }
        ws[t] = v;
    }
    __syncthreads();
    int base = x - s;  // exclusive within wave
    if (t >= 64) base += ws[(t >> 6) - 1];
    int run = base;
    for (int i = lo; i < hi; ++i) {
        rowptr[i] = run;
        run += deg[i];
    }
}

__global__ __launch_bounds__(256) void k_scatter2(const int* __restrict__ src,
                                                  const int* __restrict__ dst,
                                                  const int* __restrict__ rowptr,
                                                  int* __restrict__ cnt,
                                                  int* __restrict__ colc, int E) {
    int e = blockIdx.x * 256 + threadIdx.x;
    if (e >= E) return;
    int d = dst[e];
    int pos = rowptr[d] + atomicAdd(&cnt[d], 1);
    colc[pos] = src[e];
}

__global__ __launch_bounds__(256) void k_invdeg(const int* __restrict__ deg,
                                                float* __restrict__ inv, int n) {
    int i = blockIdx.x * 256 + threadIdx.x;
    if (i < n) inv[i] = 1.0f / (float)(deg[i] > 1 ? deg[i] : 1);
}

__global__ __launch_bounds__(256) void k_x4(const float* __restrict__ value,
                                            const float* __restrict__ u,
                                            float4* __restrict__ x4, int n) {
    int i = blockIdx.x * 256 + threadIdx.x;
    if (i < n) x4[i] = make_float4(value[i], u[2 * i], u[2 * i + 1], 0.f);
}

// ---------------------------------------------------------------- layer 1: [N,3] -> [N,64] bf16
__global__ __launch_bounds__(256) void k_l1(const float4* __restrict__ x4,
                                            const int* __restrict__ colc,
                                            const int* __restrict__ rowptr,
                                            const int* __restrict__ deg,
                                            const float* __restrict__ inv,
                                            const float* __restrict__ W1,
                                            const float* __restrict__ b1,
                                            u16* __restrict__ out, int nNodes) {
    const int lane = threadIdx.x & 63;
    const int n = blockIdx.x * 4 + (threadIdx.x >> 6);
    if (n >= nNodes) return;
    int dg = deg[n];
    const int* cl = colc + rowptr[n];
    float a0 = 0.f, a1 = 0.f, a2 = 0.f;
    for (int j = lane; j < dg; j += 64) {
        float4 v = x4[cl[j]];
        a0 += v.x; a1 += v.y; a2 += v.z;
    }
#pragma unroll
    for (int o = 32; o; o >>= 1) {
        a0 += __shfl_xor(a0, o, 64);
        a1 += __shfl_xor(a1, o, 64);
        a2 += __shfl_xor(a2, o, 64);
    }
    float iv = inv[n];
    float y = b1[lane] + iv * (a0 * W1[lane] + a1 * W1[64 + lane] + a2 * W1[128 + lane]);
    out[(size_t)n * 64 + lane] = f2bf(y);
}

// ---------------------------------------------------------------- activation
template <int ACT>
__device__ inline float actf(float x) {
    if (ACT == 1) return x > 0.f ? x : 0.01f * x;
    if (ACT == 2) return 1.f / (1.f + expf(-x));
    return x;
}

// ---------------------------------------------------------------- fused agg + GEMM per layer
// block = 256 threads (4 waves), 64 nodes/block.
// phase1: wave-per-node gather of bf16 rows -> fp32 As tile in LDS
// phase2: register-tile fp32 GEMM: Y = act(As @ W + b) -> bf16
template <int DIN, int ACT>
__global__ __launch_bounds__(256) void k_fused(const void* __restrict__ Hin,
                                               const int* __restrict__ colc,
                                               const int* __restrict__ rowptr,
                                               const int* __restrict__ deg,
                                               const float* __restrict__ inv,
                                               const float* __restrict__ W,
                                               const float* __restrict__ B,
                                               u16* __restrict__ Y, int nNodes) {
    __shared__ float As[64 * DIN];
    const int tid = threadIdx.x;
    const int lane = tid & 63;
    const int wid = tid >> 6;
    const int tile = blockIdx.x * 64;

    // ---- phase 1: gather 16 nodes per wave
    for (int i = 0; i < 16; ++i) {
        const int n = tile + wid * 16 + i;
        const int r = wid * 16 + i;
        if (n < nNodes) {
            int dg = deg[n]; if (dg > 64) dg = 64;
            const int* cl = colc + rowptr[n];
            int myc = (lane < dg) ? cl[lane] : 0;
            if (DIN == 128) {
                const u32* H32 = (const u32*)Hin;
                float a0 = 0.f, a1 = 0.f, b0 = 0.f, b1 = 0.f;
                int j = 0;
                for (; j + 4 <= dg; j += 4) {
                    int s0 = __builtin_amdgcn_readlane(myc, j);
                    int s1 = __builtin_amdgcn_readlane(myc, j + 1);
                    int s2 = __builtin_amdgcn_readlane(myc, j + 2);
                    int s3 = __builtin_amdgcn_readlane(myc, j + 3);
                    u32 v0 = H32[(size_t)s0 * 64 + lane];
                    u32 v1 = H32[(size_t)s1 * 64 + lane];
                    u32 v2 = H32[(size_t)s2 * 64 + lane];
                    u32 v3 = H32[(size_t)s3 * 64 + lane];
                    a0 += bf_lo(v0) + bf_lo(v1);
                    a1 += bf_hi(v0) + bf_hi(v1);
                    b0 += bf_lo(v2) + bf_lo(v3);
                    b1 += bf_hi(v2) + bf_hi(v3);
                }
                for (; j < dg; ++j) {
                    int s = __builtin_amdgcn_readlane(myc, j);
                    u32 v = H32[(size_t)s * 64 + lane];
                    a0 += bf_lo(v);
                    a1 += bf_hi(v);
                }
                float iv = inv[n];
                *reinterpret_cast<float2*>(&As[r * 128 + 2 * lane]) =
                    make_float2((a0 + b0) * iv, (a1 + b1) * iv);
            } else {  // DIN == 64
                const u16* H16 = (const u16*)Hin;
                float a0 = 0.f, a1 = 0.f, b0 = 0.f, b1 = 0.f;
                int j = 0;
                for (; j + 4 <= dg; j += 4) {
                    int s0 = __builtin_amdgcn_readlane(myc, j);
                    int s1 = __builtin_amdgcn_readlane(myc, j + 1);
                    int s2 = __builtin_amdgcn_readlane(myc, j + 2);
                    int s3 = __builtin_amdgcn_readlane(myc, j + 3);
                    a0 += __uint_as_float((u32)H16[(size_t)s0 * 64 + lane] << 16);
                    a1 += __uint_as_float((u32)H16[(size_t)s1 * 64 + lane] << 16);
                    b0 += __uint_as_float((u32)H16[(size_t)s2 * 64 + lane] << 16);
                    b1 += __uint_as_float((u32)H16[(size_t)s3 * 64 + lane] << 16);
                }
                for (; j < dg; ++j) {
                    int s = __builtin_amdgcn_readlane(myc, j);
                    a0 += __uint_as_float((u32)H16[(size_t)s * 64 + lane] << 16);
                }
                As[r * 64 + lane] = (a0 + a1 + b0 + b1) * inv[n];
            }
        }
    }
    __syncthreads();

    // ---- phase 2: GEMM [64,DIN] @ [DIN,128]
    const int tcol = tid & 31;
    const int trow = tid >> 5;
    const float* Wp = W + tcol * 4;
    float acc[8][4] = {};

#pragma unroll 2
    for (int i = 0; i < DIN; i += 4) {
        const float4 w0 = *reinterpret_cast<const float4*>(Wp + (size_t)(i + 0) * 128);
        const float4 w1 = *reinterpret_cast<const float4*>(Wp + (size_t)(i + 1) * 128);
        const float4 w2 = *reinterpret_cast<const float4*>(Wp + (size_t)(i + 2) * 128);
        const float4 w3 = *reinterpret_cast<const float4*>(Wp + (size_t)(i + 3) * 128);
#pragma unroll
        for (int r = 0; r < 8; ++r) {
            const float4 a = *reinterpret_cast<const float4*>(&As[(trow * 8 + r) * DIN + i]);
            acc[r][0] = fmaf(a.x, w0.x, fmaf(a.y, w1.x, fmaf(a.z, w2.x, fmaf(a.w, w3.x, acc[r][0]))));
            acc[r][1] = fmaf(a.x, w0.y, fmaf(a.y, w1.y, fmaf(a.z, w2.y, fmaf(a.w, w3.y, acc[r][1]))));
            acc[r][2] = fmaf(a.x, w0.z, fmaf(a.y, w1.z, fmaf(a.z, w2.z, fmaf(a.w, w3.z, acc[r][2]))));
            acc[r][3] = fmaf(a.x, w0.w, fmaf(a.y, w1.w, fmaf(a.z, w2.w, fmaf(a.w, w3.w, acc[r][3]))));
        }
    }

    const float4 bias = *reinterpret_cast<const float4*>(B + tcol * 4);
#pragma unroll
    for (int r = 0; r < 8; ++r) {
        int n = tile + trow * 8 + r;
        if (n < nNodes) {
            ushort4 o;
            o.x = f2bf(actf<ACT>(acc[r][0] + bias.x));
            o.y = f2bf(actf<ACT>(acc[r][1] + bias.y));
            o.z = f2bf(actf<ACT>(acc[r][2] + bias.z));
            o.w = f2bf(actf<ACT>(acc[r][3] + bias.w));
            *reinterpret_cast<ushort4*>(&Y[(size_t)n * 128 + tcol * 4]) = o;
        }
    }
}

// ---------------------------------------------------------------- layer 10: t = h @ W10
__global__ __launch_bounds__(256) void k_dot10(const u32* __restrict__ H32,
                                               const float* __restrict__ W,
                                               float* __restrict__ t, int nNodes) {
    const int lane = threadIdx.x & 63;
    const int n = blockIdx.x * 4 + (threadIdx.x >> 6);
    if (n >= nNodes) return;
    u32 v = H32[(size_t)n * 64 + lane];
    float2 w = reinterpret_cast<const float2*>(W)[lane];
    float y = bf_lo(v) * w.x + bf_hi(v) * w.y;
#pragma unroll
    for (int o = 32; o; o >>= 1) y += __shfl_xor(y, o, 64);
    if (lane == 0) t[n] = y;
}

__global__ __launch_bounds__(256) void k_aggs(const float* __restrict__ t,
                                              const int* __restrict__ colc,
                                              const int* __restrict__ rowptr,
                                              const int* __restrict__ deg,
                                              const float* __restrict__ inv,
                                              const float* __restrict__ B,
                                              float* __restrict__ out, int nNodes) {
    int n = blockIdx.x * 256 + threadIdx.x;
    if (n >= nNodes) return;
    int dg = deg[n];
    const int* cl = colc + rowptr[n];
    float s = 0.f;
    for (int j = 0; j < dg; ++j) s += t[cl[j]];
    out[n] = s * inv[n] + B[0];
}

// ---------------------------------------------------------------- host
extern "C" void kernel_launch(void* const* d_in, const int* in_sizes, int n_in,
                              void* d_out, int out_size, void* d_ws, size_t ws_size,
                              hipStream_t stream) {
    const float* value = (const float*)d_in[0];
    const float* u = (const float*)d_in[1];
    const int* src = (const int*)d_in[2];
    const int* dst = (const int*)d_in[3];
    const float* W[10];
    const float* b[10];
    for (int i = 0; i < 10; ++i) {
        W[i] = (const float*)d_in[4 + 2 * i];
        b[i] = (const float*)d_in[5 + 2 * i];
    }
    const int N = in_sizes[0];
    const int E = in_sizes[2];
    float* out = (float*)d_out;

    char* p = (char*)d_ws;
    auto carve = [&](size_t bytes) {
        char* r = p;
        p += (bytes + 255) & ~(size_t)255;
        return r;
    };
    int* deg = (int*)carve((size_t)N * 4);
    int* rowptr = (int*)carve((size_t)N * 4);
    int* cnt = (int*)carve((size_t)N * 4);
    int* colc = (int*)carve((size_t)E * 4);
    float* inv = (float*)carve((size_t)N * 4);
    float4* x4 = (float4*)carve((size_t)N * 16);
    u16* hA = (u16*)carve((size_t)N * 128 * 2);
    u16* hB = (u16*)carve((size_t)N * 128 * 2);
    float* t10 = (float*)carve((size_t)N * 4);

    hipMemsetAsync(deg, 0, (size_t)N * 4, stream);
    hipMemsetAsync(cnt, 0, (size_t)N * 4, stream);
    k_hist<<<(E + 255) / 256, 256, 0, stream>>>(dst, deg, E);
    k_scan<<<1, 1024, 0, stream>>>(deg, rowptr, N);
    k_scatter2<<<(E + 255) / 256, 256, 0, stream>>>(src, dst, rowptr, cnt, colc, E);
    k_invdeg<<<(N + 255) / 256, 256, 0, stream>>>(deg, inv, N);
    k_x4<<<(N + 255) / 256, 256, 0, stream>>>(value, u, x4, N);

    const int gw = (N + 3) / 4;
    const int gg = (N + 63) / 64;
    const int gt = (N + 255) / 256;

    // L1: [N,3] -> [N,64] bf16
    k_l1<<<gw, 256, 0, stream>>>(x4, colc, rowptr, deg, inv, W[0], b[0], hA, N);
    // L2: 64 -> 128, lrelu
    k_fused<64, 1><<<gg, 256, 0, stream>>>(hA, colc, rowptr, deg, inv, W[1], b[1], hB, N);
    // L3..L4: lrelu
    k_fused<128, 1><<<gg, 256, 0, stream>>>(hB, colc, rowptr, deg, inv, W[2], b[2], hA, N);
    k_fused<128, 1><<<gg, 256, 0, stream>>>(hA, colc, rowptr, deg, inv, W[3], b[3], hB, N);
    // L5..L8: none
    k_fused<128, 0><<<gg, 256, 0, stream>>>(hB, colc, rowptr, deg, inv, W[4], b[4], hA, N);
    k_fused<128, 0><<<gg, 256, 0, stream>>>(hA, colc, rowptr, deg, inv, W[5], b[5], hB, N);
    k_fused<128, 0><<<gg, 256, 0, stream>>>(hB, colc, rowptr, deg, inv, W[6], b[6], hA, N);
    k_fused<128, 0><<<gg, 256, 0, stream>>>(hA, colc, rowptr, deg, inv, W[7], b[7], hB, N);
    // L9: sigmoid
    k_fused<128, 2><<<gg, 256, 0, stream>>>(hB, colc, rowptr, deg, inv, W[8], b[8], hA, N);
    // L10
    k_dot10<<<gw, 256, 0, stream>>>((const u32*)hA, W[9], t10, N);
    k_aggs<<<gt, 256, 0, stream>>>(t10, colc, rowptr, deg, inv, b[9], out, N);
}

// Round 4
// 578.271 us; speedup vs baseline: 1.3726x; 1.3726x over previous
//
#include <hip/hip_runtime.h>
#include <math.h>

typedef unsigned int u32;
typedef unsigned short u16;
using bf16x8 = __attribute__((ext_vector_type(8))) short;
using f32x4 = __attribute__((ext_vector_type(4))) float;

__device__ inline float bf_lo(u32 v) { return __uint_as_float(v << 16); }
__device__ inline float bf_hi(u32 v) { return __uint_as_float(v & 0xFFFF0000u); }
__device__ inline u16 f2bf(float f) {
    u32 u = __float_as_uint(f);
    return (u16)((u + 0x7FFFu + ((u >> 16) & 1u)) >> 16);
}
__device__ inline float bf2f(u16 h) { return __uint_as_float((u32)h << 16); }

// ---------------------------------------------------------------- CSR build
__global__ __launch_bounds__(256) void k_hist(const int* __restrict__ dst,
                                              int* __restrict__ deg, int E) {
    int e = blockIdx.x * 256 + threadIdx.x;
    if (e < E) atomicAdd(&deg[dst[e]], 1);
}

__global__ __launch_bounds__(1024) void k_scan(const int* __restrict__ deg,
                                               int* __restrict__ rowptr, int n) {
    __shared__ int ws[16];
    const int t = threadIdx.x;
    const int lane = t & 63;
    const int chunk = (n + 1023) >> 10;
    const int lo = t * chunk;
    const int hi = (lo + chunk < n) ? lo + chunk : n;
    int s = 0;
    for (int i = lo; i < hi; ++i) s += deg[i];
    int x = s;
#pragma unroll
    for (int o = 1; o < 64; o <<= 1) {
        int y = __shfl_up(x, o, 64);
        if (lane >= o) x += y;
    }
    if (lane == 63) ws[t >> 6] = x;
    __syncthreads();
    if (t < 16) {
        int v = ws[t];
#pragma unroll
        for (int o = 1; o < 16; o <<= 1) {
            int y = __shfl_up(v, o, 64);
            if (lane >= o) v += y;
        }
        ws[t] = v;
    }
    __syncthreads();
    int base = x - s;
    if (t >= 64) base += ws[(t >> 6) - 1];
    int run = base;
    for (int i = lo; i < hi; ++i) {
        rowptr[i] = run;
        run += deg[i];
    }
}

__global__ __launch_bounds__(256) void k_scatter2(const int* __restrict__ src,
                                                  const int* __restrict__ dst,
                                                  const int* __restrict__ rowptr,
                                                  int* __restrict__ cnt,
                                                  int* __restrict__ colc, int E) {
    int e = blockIdx.x * 256 + threadIdx.x;
    if (e >= E) return;
    int d = dst[e];
    int pos = rowptr[d] + atomicAdd(&cnt[d], 1);
    colc[pos] = src[e];
}

__global__ __launch_bounds__(256) void k_invdeg(const int* __restrict__ deg,
                                                float* __restrict__ inv, int n) {
    int i = blockIdx.x * 256 + threadIdx.x;
    if (i < n) inv[i] = 1.0f / (float)(deg[i] > 1 ? deg[i] : 1);
}

__global__ __launch_bounds__(256) void k_x4(const float* __restrict__ value,
                                            const float* __restrict__ u,
                                            float4* __restrict__ x4, int n) {
    int i = blockIdx.x * 256 + threadIdx.x;
    if (i < n) x4[i] = make_float4(value[i], u[2 * i], u[2 * i + 1], 0.f);
}

// ---------------------------------------------------------------- W packing into MFMA B-frag layout (hi+lo split bf16)
// element (ct, ks, lane, j): k = ks*32 + (lane>>4)*8 + j ; n = ct*16 + (lane&15)
struct W7 { const float* p[7]; };

__global__ __launch_bounds__(256) void k_pack128(W7 wp, u16* __restrict__ hi,
                                                 u16* __restrict__ lo) {
    const int l = blockIdx.y;
    const float* W = wp.p[l];
    int g = blockIdx.x * 256 + threadIdx.x;  // 0..2047
    int ct = g >> 8;
    int rem = g & 255;
    int ks = rem >> 6;
    int lane = rem & 63;
    int kbase = ks * 32 + ((lane >> 4) << 3);
    int n = (ct << 4) + (lane & 15);
    size_t off = ((size_t)l * 2048 + g) * 8;
#pragma unroll
    for (int j = 0; j < 8; ++j) {
        float w = W[(size_t)(kbase + j) * 128 + n];
        u16 h = f2bf(w);
        hi[off + j] = h;
        lo[off + j] = f2bf(w - bf2f(h));
    }
}

__global__ __launch_bounds__(256) void k_pack64(const float* __restrict__ W,
                                                u16* __restrict__ hi,
                                                u16* __restrict__ lo) {
    int g = blockIdx.x * 256 + threadIdx.x;  // 0..1023
    int ct = g >> 7;
    int rem = g & 127;
    int ks = rem >> 6;
    int lane = rem & 63;
    int kbase = ks * 32 + ((lane >> 4) << 3);
    int n = (ct << 4) + (lane & 15);
    size_t off = (size_t)g * 8;
#pragma unroll
    for (int j = 0; j < 8; ++j) {
        float w = W[(size_t)(kbase + j) * 128 + n];
        u16 h = f2bf(w);
        hi[off + j] = h;
        lo[off + j] = f2bf(w - bf2f(h));
    }
}

// ---------------------------------------------------------------- layer 1: [N,3] -> [N,64] bf16
__global__ __launch_bounds__(256) void k_l1(const float4* __restrict__ x4,
                                            const int* __restrict__ colc,
                                            const int* __restrict__ rowptr,
                                            const int* __restrict__ deg,
                                            const float* __restrict__ inv,
                                            const float* __restrict__ W1,
                                            const float* __restrict__ b1,
                                            u16* __restrict__ out, int nNodes) {
    const int lane = threadIdx.x & 63;
    const int n = blockIdx.x * 4 + (threadIdx.x >> 6);
    if (n >= nNodes) return;
    int dg = deg[n];
    const int* cl = colc + rowptr[n];
    float a0 = 0.f, a1 = 0.f, a2 = 0.f;
    for (int j = lane; j < dg; j += 64) {
        float4 v = x4[cl[j]];
        a0 += v.x; a1 += v.y; a2 += v.z;
    }
#pragma unroll
    for (int o = 32; o; o >>= 1) {
        a0 += __shfl_xor(a0, o, 64);
        a1 += __shfl_xor(a1, o, 64);
        a2 += __shfl_xor(a2, o, 64);
    }
    float iv = inv[n];
    float y = b1[lane] + iv * (a0 * W1[lane] + a1 * W1[64 + lane] + a2 * W1[128 + lane]);
    out[(size_t)n * 64 + lane] = f2bf(y);
}

// ---------------------------------------------------------------- agg over bf16 rows -> bf16, 128-wide
__global__ __launch_bounds__(256) void k_agg128b(const u32* __restrict__ H32,
                                                 const int* __restrict__ colc,
                                                 const int* __restrict__ rowptr,
                                                 const int* __restrict__ deg,
                                                 const float* __restrict__ inv,
                                                 u32* __restrict__ out, int nNodes) {
    const int lane = threadIdx.x & 63;
    const int n = blockIdx.x * 4 + (threadIdx.x >> 6);
    if (n >= nNodes) return;
    int dg = deg[n]; if (dg > 64) dg = 64;
    const int* cl = colc + rowptr[n];
    int myc = (lane < dg) ? cl[lane] : 0;
    float a0 = 0.f, a1 = 0.f, b0 = 0.f, b1 = 0.f;
    int j = 0;
    for (; j + 4 <= dg; j += 4) {
        int s0 = __builtin_amdgcn_readlane(myc, j);
        int s1 = __builtin_amdgcn_readlane(myc, j + 1);
        int s2 = __builtin_amdgcn_readlane(myc, j + 2);
        int s3 = __builtin_amdgcn_readlane(myc, j + 3);
        u32 v0 = H32[(size_t)s0 * 64 + lane];
        u32 v1 = H32[(size_t)s1 * 64 + lane];
        u32 v2 = H32[(size_t)s2 * 64 + lane];
        u32 v3 = H32[(size_t)s3 * 64 + lane];
        a0 += bf_lo(v0) + bf_lo(v1);
        a1 += bf_hi(v0) + bf_hi(v1);
        b0 += bf_lo(v2) + bf_lo(v3);
        b1 += bf_hi(v2) + bf_hi(v3);
    }
    for (; j < dg; ++j) {
        int s = __builtin_amdgcn_readlane(myc, j);
        u32 v = H32[(size_t)s * 64 + lane];
        a0 += bf_lo(v);
        a1 += bf_hi(v);
    }
    float iv = inv[n];
    out[(size_t)n * 64 + lane] =
        (u32)f2bf((a0 + b0) * iv) | ((u32)f2bf((a1 + b1) * iv) << 16);
}

// ---------------------------------------------------------------- agg over bf16 rows -> bf16, 64-wide
__global__ __launch_bounds__(256) void k_agg64b(const u16* __restrict__ H16,
                                                const int* __restrict__ colc,
                                                const int* __restrict__ rowptr,
                                                const int* __restrict__ deg,
                                                const float* __restrict__ inv,
                                                u16* __restrict__ out, int nNodes) {
    const int lane = threadIdx.x & 63;
    const int n = blockIdx.x * 4 + (threadIdx.x >> 6);
    if (n >= nNodes) return;
    int dg = deg[n]; if (dg > 64) dg = 64;
    const int* cl = colc + rowptr[n];
    int myc = (lane < dg) ? cl[lane] : 0;
    float a0 = 0.f, a1 = 0.f, b0 = 0.f, b1 = 0.f;
    int j = 0;
    for (; j + 4 <= dg; j += 4) {
        int s0 = __builtin_amdgcn_readlane(myc, j);
        int s1 = __builtin_amdgcn_readlane(myc, j + 1);
        int s2 = __builtin_amdgcn_readlane(myc, j + 2);
        int s3 = __builtin_amdgcn_readlane(myc, j + 3);
        a0 += bf2f(H16[(size_t)s0 * 64 + lane]);
        a1 += bf2f(H16[(size_t)s1 * 64 + lane]);
        b0 += bf2f(H16[(size_t)s2 * 64 + lane]);
        b1 += bf2f(H16[(size_t)s3 * 64 + lane]);
    }
    for (; j < dg; ++j) {
        int s = __builtin_amdgcn_readlane(myc, j);
        a0 += bf2f(H16[(size_t)s * 64 + lane]);
    }
    out[(size_t)n * 64 + lane] = f2bf((a0 + a1 + b0 + b1) * inv[n]);
}

// ---------------------------------------------------------------- activation
template <int ACT>
__device__ inline float actf(float x) {
    if (ACT == 1) return x > 0.f ? x : 0.01f * x;
    if (ACT == 2) return 1.f / (1.f + expf(-x));
    return x;
}

// ---------------------------------------------------------------- MFMA GEMM: bf16 [N,DIN] @ packed W -> bf16 [N,128]
// block 256 = 4 waves; wave handles 16 rows; 8 col-tiles of 16; K in steps of 32.
template <int DIN, int ACT>
__global__ __launch_bounds__(256) void k_mm(const u16* __restrict__ A,
                                            const u16* __restrict__ pkHi,
                                            const u16* __restrict__ pkLo,
                                            const float* __restrict__ B,
                                            u16* __restrict__ Y, int nNodes) {
    constexpr int NKS = DIN / 32;
    const int lane = threadIdx.x & 63;
    const int w = threadIdx.x >> 6;
    const int base = blockIdx.x * 64 + w * 16;
    const int m = lane & 15;
    const int kb = lane >> 4;
    int arow = base + m;
    if (arow >= nNodes) arow = nNodes - 1;

    bf16x8 aF[NKS];
#pragma unroll
    for (int ks = 0; ks < NKS; ++ks)
        aF[ks] = *reinterpret_cast<const bf16x8*>(A + (size_t)arow * DIN + ks * 32 + kb * 8);

    const bf16x8* bh = reinterpret_cast<const bf16x8*>(pkHi);
    const bf16x8* bl = reinterpret_cast<const bf16x8*>(pkLo);

#pragma unroll
    for (int ct = 0; ct < 8; ++ct) {
        f32x4 acc = {0.f, 0.f, 0.f, 0.f};
#pragma unroll
        for (int ks = 0; ks < NKS; ++ks) {
            acc = __builtin_amdgcn_mfma_f32_16x16x32_bf16(aF[ks], bh[(ct * NKS + ks) * 64 + lane], acc, 0, 0, 0);
            acc = __builtin_amdgcn_mfma_f32_16x16x32_bf16(aF[ks], bl[(ct * NKS + ks) * 64 + lane], acc, 0, 0, 0);
        }
        float bias = B[ct * 16 + m];
#pragma unroll
        for (int r = 0; r < 4; ++r) {
            int row = base + kb * 4 + r;
            if (row < nNodes)
                Y[(size_t)row * 128 + ct * 16 + m] = f2bf(actf<ACT>(acc[r] + bias));
        }
    }
}

// ---------------------------------------------------------------- L9+L10a fused: sigmoid(h9) @ W10 -> t[N]
__global__ __launch_bounds__(256) void k_mm_last(const u16* __restrict__ A,
                                                 const u16* __restrict__ pkHi,
                                                 const u16* __restrict__ pkLo,
                                                 const float* __restrict__ B,
                                                 const float* __restrict__ w10,
                                                 float* __restrict__ t, int nNodes) {
    const int lane = threadIdx.x & 63;
    const int w = threadIdx.x >> 6;
    const int base = blockIdx.x * 64 + w * 16;
    const int m = lane & 15;
    const int kb = lane >> 4;
    int arow = base + m;
    if (arow >= nNodes) arow = nNodes - 1;

    bf16x8 aF[4];
#pragma unroll
    for (int ks = 0; ks < 4; ++ks)
        aF[ks] = *reinterpret_cast<const bf16x8*>(A + (size_t)arow * 128 + ks * 32 + kb * 8);

    const bf16x8* bh = reinterpret_cast<const bf16x8*>(pkHi);
    const bf16x8* bl = reinterpret_cast<const bf16x8*>(pkLo);

    float p0 = 0.f, p1 = 0.f, p2 = 0.f, p3 = 0.f;
#pragma unroll
    for (int ct = 0; ct < 8; ++ct) {
        f32x4 acc = {0.f, 0.f, 0.f, 0.f};
#pragma unroll
        for (int ks = 0; ks < 4; ++ks) {
            acc = __builtin_amdgcn_mfma_f32_16x16x32_bf16(aF[ks], bh[(ct * 4 + ks) * 64 + lane], acc, 0, 0, 0);
            acc = __builtin_amdgcn_mfma_f32_16x16x32_bf16(aF[ks], bl[(ct * 4 + ks) * 64 + lane], acc, 0, 0, 0);
        }
        float bias = B[ct * 16 + m];
        float wv = w10[ct * 16 + m];
        p0 += wv * actf<2>(acc[0] + bias);
        p1 += wv * actf<2>(acc[1] + bias);
        p2 += wv * actf<2>(acc[2] + bias);
        p3 += wv * actf<2>(acc[3] + bias);
    }
#pragma unroll
    for (int o = 1; o < 16; o <<= 1) {
        p0 += __shfl_xor(p0, o, 64);
        p1 += __shfl_xor(p1, o, 64);
        p2 += __shfl_xor(p2, o, 64);
        p3 += __shfl_xor(p3, o, 64);
    }
    if (m == 0) {
        int r0 = base + kb * 4;
        if (r0 + 0 < nNodes) t[r0 + 0] = p0;
        if (r0 + 1 < nNodes) t[r0 + 1] = p1;
        if (r0 + 2 < nNodes) t[r0 + 2] = p2;
        if (r0 + 3 < nNodes) t[r0 + 3] = p3;
    }
}

// ---------------------------------------------------------------- L10b: out = inv * sum(t[src]) + b10
__global__ __launch_bounds__(256) void k_aggs(const float* __restrict__ t,
                                              const int* __restrict__ colc,
                                              const int* __restrict__ rowptr,
                                              const int* __restrict__ deg,
                                              const float* __restrict__ inv,
                                              const float* __restrict__ B,
                                              float* __restrict__ out, int nNodes) {
    int n = blockIdx.x * 256 + threadIdx.x;
    if (n >= nNodes) return;
    int dg = deg[n];
    const int* cl = colc + rowptr[n];
    float s = 0.f;
    for (int j = 0; j < dg; ++j) s += t[cl[j]];
    out[n] = s * inv[n] + B[0];
}

// ---------------------------------------------------------------- host
extern "C" void kernel_launch(void* const* d_in, const int* in_sizes, int n_in,
                              void* d_out, int out_size, void* d_ws, size_t ws_size,
                              hipStream_t stream) {
    const float* value = (const float*)d_in[0];
    const float* u = (const float*)d_in[1];
    const int* src = (const int*)d_in[2];
    const int* dst = (const int*)d_in[3];
    const float* W[10];
    const float* b[10];
    for (int i = 0; i < 10; ++i) {
        W[i] = (const float*)d_in[4 + 2 * i];
        b[i] = (const float*)d_in[5 + 2 * i];
    }
    const int N = in_sizes[0];
    const int E = in_sizes[2];
    float* out = (float*)d_out;

    char* p = (char*)d_ws;
    auto carve = [&](size_t bytes) {
        char* r = p;
        p += (bytes + 255) & ~(size_t)255;
        return r;
    };
    int* deg = (int*)carve((size_t)N * 4);
    int* rowptr = (int*)carve((size_t)N * 4);
    int* cnt = (int*)carve((size_t)N * 4);
    int* colc = (int*)carve((size_t)E * 4);
    float* inv = (float*)carve((size_t)N * 4);
    float4* x4 = (float4*)carve((size_t)N * 16);
    u16* hA = (u16*)carve((size_t)N * 128 * 2);
    u16* hB = (u16*)carve((size_t)N * 128 * 2);
    u16* agg = (u16*)carve((size_t)N * 128 * 2);
    float* t10 = (float*)carve((size_t)N * 4);
    u16* pk128hi = (u16*)carve((size_t)7 * 2048 * 8 * 2);
    u16* pk128lo = (u16*)carve((size_t)7 * 2048 * 8 * 2);
    u16* pk64hi = (u16*)carve((size_t)1024 * 8 * 2);
    u16* pk64lo = (u16*)carve((size_t)1024 * 8 * 2);

    hipMemsetAsync(deg, 0, (size_t)N * 4, stream);
    hipMemsetAsync(cnt, 0, (size_t)N * 4, stream);
    k_hist<<<(E + 255) / 256, 256, 0, stream>>>(dst, deg, E);
    k_scan<<<1, 1024, 0, stream>>>(deg, rowptr, N);
    k_scatter2<<<(E + 255) / 256, 256, 0, stream>>>(src, dst, rowptr, cnt, colc, E);
    k_invdeg<<<(N + 255) / 256, 256, 0, stream>>>(deg, inv, N);
    k_x4<<<(N + 255) / 256, 256, 0, stream>>>(value, u, x4, N);

    W7 wp;
    for (int i = 0; i < 7; ++i) wp.p[i] = W[2 + i];  // W3..W9
    k_pack128<<<dim3(8, 7), 256, 0, stream>>>(wp, pk128hi, pk128lo);
    k_pack64<<<4, 256, 0, stream>>>(W[1], pk64hi, pk64lo);

    const int gw = (N + 3) / 4;
    const int gg = (N + 63) / 64;
    const int gt = (N + 255) / 256;
    const size_t PK = 2048 * 8;  // u16 per 128-layer pack

    // L1: [N,3] -> [N,64] bf16
    k_l1<<<gw, 256, 0, stream>>>(x4, colc, rowptr, deg, inv, W[0], b[0], hA, N);
    // L2: 64 -> 128, lrelu
    k_agg64b<<<gw, 256, 0, stream>>>(hA, colc, rowptr, deg, inv, agg, N);
    k_mm<64, 1><<<gg, 256, 0, stream>>>(agg, pk64hi, pk64lo, b[1], hB, N);
    // L3, L4: lrelu
    k_agg128b<<<gw, 256, 0, stream>>>((const u32*)hB, colc, rowptr, deg, inv, (u32*)agg, N);
    k_mm<128, 1><<<gg, 256, 0, stream>>>(agg, pk128hi + 0 * PK, pk128lo + 0 * PK, b[2], hA, N);
    k_agg128b<<<gw, 256, 0, stream>>>((const u32*)hA, colc, rowptr, deg, inv, (u32*)agg, N);
    k_mm<128, 1><<<gg, 256, 0, stream>>>(agg, pk128hi + 1 * PK, pk128lo + 1 * PK, b[3], hB, N);
    // L5..L8: none
    k_agg128b<<<gw, 256, 0, stream>>>((const u32*)hB, colc, rowptr, deg, inv, (u32*)agg, N);
    k_mm<128, 0><<<gg, 256, 0, stream>>>(agg, pk128hi + 2 * PK, pk128lo + 2 * PK, b[4], hA, N);
    k_agg128b<<<gw, 256, 0, stream>>>((const u32*)hA, colc, rowptr, deg, inv, (u32*)agg, N);
    k_mm<128, 0><<<gg, 256, 0, stream>>>(agg, pk128hi + 3 * PK, pk128lo + 3 * PK, b[5], hB, N);
    k_agg128b<<<gw, 256, 0, stream>>>((const u32*)hB, colc, rowptr, deg, inv, (u32*)agg, N);
    k_mm<128, 0><<<gg, 256, 0, stream>>>(agg, pk128hi + 4 * PK, pk128lo + 4 * PK, b[6], hA, N);
    k_agg128b<<<gw, 256, 0, stream>>>((const u32*)hA, colc, rowptr, deg, inv, (u32*)agg, N);
    k_mm<128, 0><<<gg, 256, 0, stream>>>(agg, pk128hi + 5 * PK, pk128lo + 5 * PK, b[7], hB, N);
    // L9 + L10a: sigmoid + dot W10 -> t
    k_agg128b<<<gw, 256, 0, stream>>>((const u32*)hB, colc, rowptr, deg, inv, (u32*)agg, N);
    k_mm_last<<<gg, 256, 0, stream>>>(agg, pk128hi + 6 * PK, pk128lo + 6 * PK, b[8], W[9], t10, N);
    // L10b
    k_aggs<<<gt, 256, 0, stream>>>(t10, colc, rowptr, deg, inv, b[9], out, N);
}

// Round 5
// 489.421 us; speedup vs baseline: 1.6217x; 1.1815x over previous
//
#include <hip/hip_runtime.h>
#include <math.h>

typedef unsigned int u32;
typedef unsigned short u16;
using bf16x8 = __attribute__((ext_vector_type(8))) short;
using f32x4 = __attribute__((ext_vector_type(4))) float;

__device__ inline float bf_lo(u32 v) { return __uint_as_float(v << 16); }
__device__ inline float bf_hi(u32 v) { return __uint_as_float(v & 0xFFFF0000u); }
__device__ inline u16 f2bf(float f) {
    u32 u = __float_as_uint(f);
    return (u16)((u + 0x7FFFu + ((u >> 16) & 1u)) >> 16);
}
__device__ inline float bf2f(u16 h) { return __uint_as_float((u32)h << 16); }

// ---------------------------------------------------------------- CSR build
__global__ __launch_bounds__(256) void k_hist(const int* __restrict__ dst,
                                              int* __restrict__ deg, int E) {
    int e = blockIdx.x * 256 + threadIdx.x;
    if (e < E) atomicAdd(&deg[dst[e]], 1);
}

// pass 1: per-block exclusive scan of deg -> rowptr (local), block totals -> bsum.
// fused: inv_deg and x4 feature build (same index space).
__global__ __launch_bounds__(256) void k_s1(const int* __restrict__ deg,
                                            int* __restrict__ rowptr,
                                            int* __restrict__ bsum,
                                            float* __restrict__ inv,
                                            const float* __restrict__ value,
                                            const float* __restrict__ u,
                                            float4* __restrict__ x4, int n) {
    __shared__ int wt[4];
    const int t = threadIdx.x;
    const int lane = t & 63;
    const int w = t >> 6;
    const int i = blockIdx.x * 256 + t;
    int d = (i < n) ? deg[i] : 0;
    int x = d;
#pragma unroll
    for (int o = 1; o < 64; o <<= 1) {
        int y = __shfl_up(x, o, 64);
        if (lane >= o) x += y;
    }
    if (lane == 63) wt[w] = x;
    __syncthreads();
    int add = 0;
    for (int k = 0; k < w; ++k) add += wt[k];
    int incl = x + add;
    if (i < n) {
        rowptr[i] = incl - d;
        inv[i] = 1.0f / (float)(d > 1 ? d : 1);
        x4[i] = make_float4(value[i], u[2 * i], u[2 * i + 1], 0.f);
    }
    if (t == 255) bsum[blockIdx.x] = incl;
}

// pass 2: single block (1024 threads) exclusive scan of block sums, in place
__global__ __launch_bounds__(1024) void k_s2(int* __restrict__ bsum, int nb) {
    __shared__ int wt[16];
    const int t = threadIdx.x;
    const int lane = t & 63;
    const int w = t >> 6;
    int d = (t < nb) ? bsum[t] : 0;
    int x = d;
#pragma unroll
    for (int o = 1; o < 64; o <<= 1) {
        int y = __shfl_up(x, o, 64);
        if (lane >= o) x += y;
    }
    if (lane == 63) wt[w] = x;
    __syncthreads();
    int add = 0;
    for (int k = 0; k < w; ++k) add += wt[k];
    if (t < nb) bsum[t] = x + add - d;
}

// pass 3: add block offsets
__global__ __launch_bounds__(256) void k_s3(int* __restrict__ rowptr,
                                            const int* __restrict__ bsum, int n) {
    int i = blockIdx.x * 256 + threadIdx.x;
    if (i < n) rowptr[i] += bsum[blockIdx.x];
}

__global__ __launch_bounds__(256) void k_scatter2(const int* __restrict__ src,
                                                  const int* __restrict__ dst,
                                                  const int* __restrict__ rowptr,
                                                  int* __restrict__ cnt,
                                                  int* __restrict__ colc, int E) {
    int e = blockIdx.x * 256 + threadIdx.x;
    if (e >= E) return;
    int d = dst[e];
    int pos = rowptr[d] + atomicAdd(&cnt[d], 1);
    colc[pos] = src[e];
}

// ---------------------------------------------------------------- W packing into MFMA B-frag layout (hi+lo split bf16)
struct W7 { const float* p[7]; };

__global__ __launch_bounds__(256) void k_pack128(W7 wp, u16* __restrict__ hi,
                                                 u16* __restrict__ lo) {
    const int l = blockIdx.y;
    const float* W = wp.p[l];
    int g = blockIdx.x * 256 + threadIdx.x;  // 0..2047
    int ct = g >> 8;
    int rem = g & 255;
    int ks = rem >> 6;
    int lane = rem & 63;
    int kbase = ks * 32 + ((lane >> 4) << 3);
    int n = (ct << 4) + (lane & 15);
    size_t off = ((size_t)l * 2048 + g) * 8;
#pragma unroll
    for (int j = 0; j < 8; ++j) {
        float w = W[(size_t)(kbase + j) * 128 + n];
        u16 h = f2bf(w);
        hi[off + j] = h;
        lo[off + j] = f2bf(w - bf2f(h));
    }
}

__global__ __launch_bounds__(256) void k_pack64(const float* __restrict__ W,
                                                u16* __restrict__ hi,
                                                u16* __restrict__ lo) {
    int g = blockIdx.x * 256 + threadIdx.x;  // 0..1023
    int ct = g >> 7;
    int rem = g & 127;
    int ks = rem >> 6;
    int lane = rem & 63;
    int kbase = ks * 32 + ((lane >> 4) << 3);
    int n = (ct << 4) + (lane & 15);
    size_t off = (size_t)g * 8;
#pragma unroll
    for (int j = 0; j < 8; ++j) {
        float w = W[(size_t)(kbase + j) * 128 + n];
        u16 h = f2bf(w);
        hi[off + j] = h;
        lo[off + j] = f2bf(w - bf2f(h));
    }
}

// ---------------------------------------------------------------- layer 1: [N,3] -> [N,64] bf16
__global__ __launch_bounds__(256) void k_l1(const float4* __restrict__ x4,
                                            const int* __restrict__ colc,
                                            const int* __restrict__ rowptr,
                                            const int* __restrict__ deg,
                                            const float* __restrict__ inv,
                                            const float* __restrict__ W1,
                                            const float* __restrict__ b1,
                                            u16* __restrict__ out, int nNodes) {
    const int lane = threadIdx.x & 63;
    const int n = blockIdx.x * 4 + (threadIdx.x >> 6);
    if (n >= nNodes) return;
    int dg = deg[n];
    const int* cl = colc + rowptr[n];
    float a0 = 0.f, a1 = 0.f, a2 = 0.f;
    for (int j = lane; j < dg; j += 64) {
        float4 v = x4[cl[j]];
        a0 += v.x; a1 += v.y; a2 += v.z;
    }
#pragma unroll
    for (int o = 32; o; o >>= 1) {
        a0 += __shfl_xor(a0, o, 64);
        a1 += __shfl_xor(a1, o, 64);
        a2 += __shfl_xor(a2, o, 64);
    }
    float iv = inv[n];
    float y = b1[lane] + iv * (a0 * W1[lane] + a1 * W1[64 + lane] + a2 * W1[128 + lane]);
    out[(size_t)n * 64 + lane] = f2bf(y);
}

// ---------------------------------------------------------------- agg over bf16 rows -> bf16, 128-wide (8 loads in flight)
__global__ __launch_bounds__(256) void k_agg128b(const u32* __restrict__ H32,
                                                 const int* __restrict__ colc,
                                                 const int* __restrict__ rowptr,
                                                 const int* __restrict__ deg,
                                                 const float* __restrict__ inv,
                                                 u32* __restrict__ out, int nNodes) {
    const int lane = threadIdx.x & 63;
    const int n = blockIdx.x * 4 + (threadIdx.x >> 6);
    if (n >= nNodes) return;
    int dg = deg[n]; if (dg > 64) dg = 64;
    const int* cl = colc + rowptr[n];
    int myc = (lane < dg) ? cl[lane] : 0;
    float a0 = 0.f, a1 = 0.f, b0 = 0.f, b1 = 0.f;
    int j = 0;
    for (; j + 8 <= dg; j += 8) {
        u32 v0 = H32[(size_t)__builtin_amdgcn_readlane(myc, j + 0) * 64 + lane];
        u32 v1 = H32[(size_t)__builtin_amdgcn_readlane(myc, j + 1) * 64 + lane];
        u32 v2 = H32[(size_t)__builtin_amdgcn_readlane(myc, j + 2) * 64 + lane];
        u32 v3 = H32[(size_t)__builtin_amdgcn_readlane(myc, j + 3) * 64 + lane];
        u32 v4 = H32[(size_t)__builtin_amdgcn_readlane(myc, j + 4) * 64 + lane];
        u32 v5 = H32[(size_t)__builtin_amdgcn_readlane(myc, j + 5) * 64 + lane];
        u32 v6 = H32[(size_t)__builtin_amdgcn_readlane(myc, j + 6) * 64 + lane];
        u32 v7 = H32[(size_t)__builtin_amdgcn_readlane(myc, j + 7) * 64 + lane];
        a0 += bf_lo(v0) + bf_lo(v1) + bf_lo(v2) + bf_lo(v3);
        a1 += bf_hi(v0) + bf_hi(v1) + bf_hi(v2) + bf_hi(v3);
        b0 += bf_lo(v4) + bf_lo(v5) + bf_lo(v6) + bf_lo(v7);
        b1 += bf_hi(v4) + bf_hi(v5) + bf_hi(v6) + bf_hi(v7);
    }
    for (; j + 4 <= dg; j += 4) {
        u32 v0 = H32[(size_t)__builtin_amdgcn_readlane(myc, j + 0) * 64 + lane];
        u32 v1 = H32[(size_t)__builtin_amdgcn_readlane(myc, j + 1) * 64 + lane];
        u32 v2 = H32[(size_t)__builtin_amdgcn_readlane(myc, j + 2) * 64 + lane];
        u32 v3 = H32[(size_t)__builtin_amdgcn_readlane(myc, j + 3) * 64 + lane];
        a0 += bf_lo(v0) + bf_lo(v1);
        a1 += bf_hi(v0) + bf_hi(v1);
        b0 += bf_lo(v2) + bf_lo(v3);
        b1 += bf_hi(v2) + bf_hi(v3);
    }
    for (; j < dg; ++j) {
        u32 v = H32[(size_t)__builtin_amdgcn_readlane(myc, j) * 64 + lane];
        a0 += bf_lo(v);
        a1 += bf_hi(v);
    }
    float iv = inv[n];
    out[(size_t)n * 64 + lane] =
        (u32)f2bf((a0 + b0) * iv) | ((u32)f2bf((a1 + b1) * iv) << 16);
}

// ---------------------------------------------------------------- agg over bf16 rows -> bf16, 64-wide
__global__ __launch_bounds__(256) void k_agg64b(const u16* __restrict__ H16,
                                                const int* __restrict__ colc,
                                                const int* __restrict__ rowptr,
                                                const int* __restrict__ deg,
                                                const float* __restrict__ inv,
                                                u16* __restrict__ out, int nNodes) {
    const int lane = threadIdx.x & 63;
    const int n = blockIdx.x * 4 + (threadIdx.x >> 6);
    if (n >= nNodes) return;
    int dg = deg[n]; if (dg > 64) dg = 64;
    const int* cl = colc + rowptr[n];
    int myc = (lane < dg) ? cl[lane] : 0;
    float a0 = 0.f, a1 = 0.f, b0 = 0.f, b1 = 0.f;
    int j = 0;
    for (; j + 8 <= dg; j += 8) {
        u16 v0 = H16[(size_t)__builtin_amdgcn_readlane(myc, j + 0) * 64 + lane];
        u16 v1 = H16[(size_t)__builtin_amdgcn_readlane(myc, j + 1) * 64 + lane];
        u16 v2 = H16[(size_t)__builtin_amdgcn_readlane(myc, j + 2) * 64 + lane];
        u16 v3 = H16[(size_t)__builtin_amdgcn_readlane(myc, j + 3) * 64 + lane];
        u16 v4 = H16[(size_t)__builtin_amdgcn_readlane(myc, j + 4) * 64 + lane];
        u16 v5 = H16[(size_t)__builtin_amdgcn_readlane(myc, j + 5) * 64 + lane];
        u16 v6 = H16[(size_t)__builtin_amdgcn_readlane(myc, j + 6) * 64 + lane];
        u16 v7 = H16[(size_t)__builtin_amdgcn_readlane(myc, j + 7) * 64 + lane];
        a0 += bf2f(v0) + bf2f(v1);
        a1 += bf2f(v2) + bf2f(v3);
        b0 += bf2f(v4) + bf2f(v5);
        b1 += bf2f(v6) + bf2f(v7);
    }
    for (; j + 4 <= dg; j += 4) {
        u16 v0 = H16[(size_t)__builtin_amdgcn_readlane(myc, j + 0) * 64 + lane];
        u16 v1 = H16[(size_t)__builtin_amdgcn_readlane(myc, j + 1) * 64 + lane];
        u16 v2 = H16[(size_t)__builtin_amdgcn_readlane(myc, j + 2) * 64 + lane];
        u16 v3 = H16[(size_t)__builtin_amdgcn_readlane(myc, j + 3) * 64 + lane];
        a0 += bf2f(v0) + bf2f(v1);
        b0 += bf2f(v2) + bf2f(v3);
    }
    for (; j < dg; ++j) {
        a0 += bf2f(H16[(size_t)__builtin_amdgcn_readlane(myc, j) * 64 + lane]);
    }
    out[(size_t)n * 64 + lane] = f2bf((a0 + a1 + b0 + b1) * inv[n]);
}

// ---------------------------------------------------------------- activation
template <int ACT>
__device__ inline float actf(float x) {
    if (ACT == 1) return x > 0.f ? x : 0.01f * x;
    if (ACT == 2) return 1.f / (1.f + expf(-x));
    return x;
}

// ---------------------------------------------------------------- MFMA GEMM: bf16 [N,DIN] @ packed W -> bf16 [N,128]
template <int DIN, int ACT>
__global__ __launch_bounds__(256) void k_mm(const u16* __restrict__ A,
                                            const u16* __restrict__ pkHi,
                                            const u16* __restrict__ pkLo,
                                            const float* __restrict__ B,
                                            u16* __restrict__ Y, int nNodes) {
    constexpr int NKS = DIN / 32;
    const int lane = threadIdx.x & 63;
    const int w = threadIdx.x >> 6;
    const int base = blockIdx.x * 64 + w * 16;
    const int m = lane & 15;
    const int kb = lane >> 4;
    int arow = base + m;
    if (arow >= nNodes) arow = nNodes - 1;

    bf16x8 aF[NKS];
#pragma unroll
    for (int ks = 0; ks < NKS; ++ks)
        aF[ks] = *reinterpret_cast<const bf16x8*>(A + (size_t)arow * DIN + ks * 32 + kb * 8);

    const bf16x8* bh = reinterpret_cast<const bf16x8*>(pkHi);
    const bf16x8* bl = reinterpret_cast<const bf16x8*>(pkLo);

#pragma unroll
    for (int ct = 0; ct < 8; ++ct) {
        f32x4 acc = {0.f, 0.f, 0.f, 0.f};
#pragma unroll
        for (int ks = 0; ks < NKS; ++ks) {
            acc = __builtin_amdgcn_mfma_f32_16x16x32_bf16(aF[ks], bh[(ct * NKS + ks) * 64 + lane], acc, 0, 0, 0);
            acc = __builtin_amdgcn_mfma_f32_16x16x32_bf16(aF[ks], bl[(ct * NKS + ks) * 64 + lane], acc, 0, 0, 0);
        }
        float bias = B[ct * 16 + m];
#pragma unroll
        for (int r = 0; r < 4; ++r) {
            int row = base + kb * 4 + r;
            if (row < nNodes)
                Y[(size_t)row * 128 + ct * 16 + m] = f2bf(actf<ACT>(acc[r] + bias));
        }
    }
}

// ---------------------------------------------------------------- L9+L10a fused: sigmoid(h9) @ W10 -> t[N]
__global__ __launch_bounds__(256) void k_mm_last(const u16* __restrict__ A,
                                                 const u16* __restrict__ pkHi,
                                                 const u16* __restrict__ pkLo,
                                                 const float* __restrict__ B,
                                                 const float* __restrict__ w10,
                                                 float* __restrict__ t, int nNodes) {
    const int lane = threadIdx.x & 63;
    const int w = threadIdx.x >> 6;
    const int base = blockIdx.x * 64 + w * 16;
    const int m = lane & 15;
    const int kb = lane >> 4;
    int arow = base + m;
    if (arow >= nNodes) arow = nNodes - 1;

    bf16x8 aF[4];
#pragma unroll
    for (int ks = 0; ks < 4; ++ks)
        aF[ks] = *reinterpret_cast<const bf16x8*>(A + (size_t)arow * 128 + ks * 32 + kb * 8);

    const bf16x8* bh = reinterpret_cast<const bf16x8*>(pkHi);
    const bf16x8* bl = reinterpret_cast<const bf16x8*>(pkLo);

    float p0 = 0.f, p1 = 0.f, p2 = 0.f, p3 = 0.f;
#pragma unroll
    for (int ct = 0; ct < 8; ++ct) {
        f32x4 acc = {0.f, 0.f, 0.f, 0.f};
#pragma unroll
        for (int ks = 0; ks < 4; ++ks) {
            acc = __builtin_amdgcn_mfma_f32_16x16x32_bf16(aF[ks], bh[(ct * 4 + ks) * 64 + lane], acc, 0, 0, 0);
            acc = __builtin_amdgcn_mfma_f32_16x16x32_bf16(aF[ks], bl[(ct * 4 + ks) * 64 + lane], acc, 0, 0, 0);
        }
        float bias = B[ct * 16 + m];
        float wv = w10[ct * 16 + m];
        p0 += wv * actf<2>(acc[0] + bias);
        p1 += wv * actf<2>(acc[1] + bias);
        p2 += wv * actf<2>(acc[2] + bias);
        p3 += wv * actf<2>(acc[3] + bias);
    }
#pragma unroll
    for (int o = 1; o < 16; o <<= 1) {
        p0 += __shfl_xor(p0, o, 64);
        p1 += __shfl_xor(p1, o, 64);
        p2 += __shfl_xor(p2, o, 64);
        p3 += __shfl_xor(p3, o, 64);
    }
    if (m == 0) {
        int r0 = base + kb * 4;
        if (r0 + 0 < nNodes) t[r0 + 0] = p0;
        if (r0 + 1 < nNodes) t[r0 + 1] = p1;
        if (r0 + 2 < nNodes) t[r0 + 2] = p2;
        if (r0 + 3 < nNodes) t[r0 + 3] = p3;
    }
}

// ---------------------------------------------------------------- L10b: out = inv * sum(t[src]) + b10
__global__ __launch_bounds__(256) void k_aggs(const float* __restrict__ t,
                                              const int* __restrict__ colc,
                                              const int* __restrict__ rowptr,
                                              const int* __restrict__ deg,
                                              const float* __restrict__ inv,
                                              const float* __restrict__ B,
                                              float* __restrict__ out, int nNodes) {
    int n = blockIdx.x * 256 + threadIdx.x;
    if (n >= nNodes) return;
    int dg = deg[n];
    const int* cl = colc + rowptr[n];
    float s = 0.f;
    for (int j = 0; j < dg; ++j) s += t[cl[j]];
    out[n] = s * inv[n] + B[0];
}

// ---------------------------------------------------------------- host
extern "C" void kernel_launch(void* const* d_in, const int* in_sizes, int n_in,
                              void* d_out, int out_size, void* d_ws, size_t ws_size,
                              hipStream_t stream) {
    const float* value = (const float*)d_in[0];
    const float* u = (const float*)d_in[1];
    const int* src = (const int*)d_in[2];
    const int* dst = (const int*)d_in[3];
    const float* W[10];
    const float* b[10];
    for (int i = 0; i < 10; ++i) {
        W[i] = (const float*)d_in[4 + 2 * i];
        b[i] = (const float*)d_in[5 + 2 * i];
    }
    const int N = in_sizes[0];
    const int E = in_sizes[2];
    float* out = (float*)d_out;

    char* p = (char*)d_ws;
    auto carve = [&](size_t bytes) {
        char* r = p;
        p += (bytes + 255) & ~(size_t)255;
        return r;
    };
    int* deg = (int*)carve((size_t)N * 4);
    int* rowptr = (int*)carve((size_t)N * 4);
    int* cnt = (int*)carve((size_t)N * 4);
    int* bsum = (int*)carve((size_t)1024 * 4);
    int* colc = (int*)carve((size_t)E * 4);
    float* inv = (float*)carve((size_t)N * 4);
    float4* x4 = (float4*)carve((size_t)N * 16);
    u16* hA = (u16*)carve((size_t)N * 128 * 2);
    u16* hB = (u16*)carve((size_t)N * 128 * 2);
    u16* agg = (u16*)carve((size_t)N * 128 * 2);
    float* t10 = (float*)carve((size_t)N * 4);
    u16* pk128hi = (u16*)carve((size_t)7 * 2048 * 8 * 2);
    u16* pk128lo = (u16*)carve((size_t)7 * 2048 * 8 * 2);
    u16* pk64hi = (u16*)carve((size_t)1024 * 8 * 2);
    u16* pk64lo = (u16*)carve((size_t)1024 * 8 * 2);

    const int NB = (N + 255) / 256;

    hipMemsetAsync(deg, 0, (size_t)N * 4, stream);
    hipMemsetAsync(cnt, 0, (size_t)N * 4, stream);
    k_hist<<<(E + 255) / 256, 256, 0, stream>>>(dst, deg, E);
    k_s1<<<NB, 256, 0, stream>>>(deg, rowptr, bsum, inv, value, u, x4, N);
    k_s2<<<1, 1024, 0, stream>>>(bsum, NB);
    k_s3<<<NB, 256, 0, stream>>>(rowptr, bsum, N);
    k_scatter2<<<(E + 255) / 256, 256, 0, stream>>>(src, dst, rowptr, cnt, colc, E);

    W7 wp;
    for (int i = 0; i < 7; ++i) wp.p[i] = W[2 + i];  // W3..W9
    k_pack128<<<dim3(8, 7), 256, 0, stream>>>(wp, pk128hi, pk128lo);
    k_pack64<<<4, 256, 0, stream>>>(W[1], pk64hi, pk64lo);

    const int gw = (N + 3) / 4;
    const int gg = (N + 63) / 64;
    const int gt = (N + 255) / 256;
    const size_t PK = 2048 * 8;  // u16 per 128-layer pack

    // L1: [N,3] -> [N,64] bf16
    k_l1<<<gw, 256, 0, stream>>>(x4, colc, rowptr, deg, inv, W[0], b[0], hA, N);
    // L2: 64 -> 128, lrelu
    k_agg64b<<<gw, 256, 0, stream>>>(hA, colc, rowptr, deg, inv, agg, N);
    k_mm<64, 1><<<gg, 256, 0, stream>>>(agg, pk64hi, pk64lo, b[1], hB, N);
    // L3, L4: lrelu
    k_agg128b<<<gw, 256, 0, stream>>>((const u32*)hB, colc, rowptr, deg, inv, (u32*)agg, N);
    k_mm<128, 1><<<gg, 256, 0, stream>>>(agg, pk128hi + 0 * PK, pk128lo + 0 * PK, b[2], hA, N);
    k_agg128b<<<gw, 256, 0, stream>>>((const u32*)hA, colc, rowptr, deg, inv, (u32*)agg, N);
    k_mm<128, 1><<<gg, 256, 0, stream>>>(agg, pk128hi + 1 * PK, pk128lo + 1 * PK, b[3], hB, N);
    // L5..L8: none
    k_agg128b<<<gw, 256, 0, stream>>>((const u32*)hB, colc, rowptr, deg, inv, (u32*)agg, N);
    k_mm<128, 0><<<gg, 256, 0, stream>>>(agg, pk128hi + 2 * PK, pk128lo + 2 * PK, b[4], hA, N);
    k_agg128b<<<gw, 256, 0, stream>>>((const u32*)hA, colc, rowptr, deg, inv, (u32*)agg, N);
    k_mm<128, 0><<<gg, 256, 0, stream>>>(agg, pk128hi + 3 * PK, pk128lo + 3 * PK, b[5], hB, N);
    k_agg128b<<<gw, 256, 0, stream>>>((const u32*)hB, colc, rowptr, deg, inv, (u32*)agg, N);
    k_mm<128, 0><<<gg, 256, 0, stream>>>(agg, pk128hi + 4 * PK, pk128lo + 4 * PK, b[6], hA, N);
    k_agg128b<<<gw, 256, 0, stream>>>((const u32*)hA, colc, rowptr, deg, inv, (u32*)agg, N);
    k_mm<128, 0><<<gg, 256, 0, stream>>>(agg, pk128hi + 5 * PK, pk128lo + 5 * PK, b[7], hB, N);
    // L9 + L10a: sigmoid + dot W10 -> t
    k_agg128b<<<gw, 256, 0, stream>>>((const u32*)hB, colc, rowptr, deg, inv, (u32*)agg, N);
    k_mm_last<<<gg, 256, 0, stream>>>(agg, pk128hi + 6 * PK, pk128lo + 6 * PK, b[8], W[9], t10, N);
    // L10b
    k_aggs<<<gt, 256, 0, stream>>>(t10, colc, rowptr, deg, inv, b[9], out, N);
}